// Round 14
// baseline (423.584 us; speedup 1.0000x reference)
//
#include <hip/hip_runtime.h>

// Receiver_46076409152346 — v10b (resubmitted unchanged; round 13 was an
// infra failure: GPU acquisition timeout — no signal on this code).
// Single persistent kernel, RELAXED-poll grid barrier (fix of v5's
// acquire-poll cache-poisoning), v9-verified phase bodies.
// Contract: inputs float32, outputs float32.
//
// Collapse identity: pair_left[r,c] = new_state[r>>11, (r>>2)&511] (const per row)
//  => y[bi,rr] = b_y2 + sum_j w_y2[j]*relu(v*ws1[j] + G[rr,j]),
//     v = ns[bi][rr>>2], ws1[j] = sum_{c<512} w_y1[j,c],
//     G[rr,j] = b_y1[j] + sum_c desc[rr,c]*w_y1[j,512+c].
//
// v10 (profile-driven): v9 = 187us; top-5 all harness fill (41us) and ~95us
// is 8x serialized dispatch gaps. v5's persistent attempt died from ACQUIRE
// polling (per-poll L2 invalidate by ~200 idle blocks; FETCH 28MB). Now:
// poll RELAXED + s_sleep, single acquire fence after wake. Phases: A =
// gru+ws1+g (no barrier between: g independent of gru) | B ystop | C dipart
// | D direduce | E ms | F msg+stop. 5 barriers, 1 launch + 8B memset.

#define NBLK 256

struct Params {
  const float *message, *state, *desc;
  const float *w_ih, *w_hh, *b_ih, *b_hh;
  const float *w_stop, *b_stop;
  const float *w_y1, *b_y1, *w_y2, *b_y2;
  const float *w_state, *b_state, *w_desc, *w_msg, *b_msg;
  float *out_stopbit, *out_stopdist, *out_msg, *out_msgdist, *out_y;
  float *ns, *nsT, *ws1, *dp, *sump, *di, *ms;
  int *bar;  // [0]=count, [1]=generation; memset to 0 before each launch
};

__device__ __forceinline__ float sigm(float x) { return 1.0f / (1.0f + expf(-x)); }

__device__ __forceinline__ void stage_pad68(float* dst, const float* src, int c) {
  *(float4*)&dst[(c >> 4) * 68 + (c & 15) * 4] = *(const float4*)&src[c * 4];
}

// Grid barrier: release fence + arrive; poll generation with RELAXED loads
// (no per-poll cache invalidate — v5's bug); one ACQUIRE fence after wake.
__device__ __forceinline__ void grid_barrier(int* bar) {
  __syncthreads();
  __threadfence();  // release our stores device-wide
  if (threadIdx.x == 0) {
    int g = __hip_atomic_load(bar + 1, __ATOMIC_RELAXED, __HIP_MEMORY_SCOPE_AGENT);
    int a = __hip_atomic_fetch_add(bar, 1, __ATOMIC_ACQ_REL, __HIP_MEMORY_SCOPE_AGENT);
    if (a == NBLK - 1) {
      __hip_atomic_store(bar, 0, __ATOMIC_RELAXED, __HIP_MEMORY_SCOPE_AGENT);
      __hip_atomic_store(bar + 1, g + 1, __ATOMIC_RELEASE, __HIP_MEMORY_SCOPE_AGENT);
    } else {
      while (__hip_atomic_load(bar + 1, __ATOMIC_RELAXED, __HIP_MEMORY_SCOPE_AGENT) == g) {
        __builtin_amdgcn_s_sleep(4);
      }
      __builtin_amdgcn_fence(__ATOMIC_ACQUIRE, "agent");  // one invalidate after wake
    }
  }
  __syncthreads();
}

// ---------------- Phase A1: GRU. h = blk, blk+256. (v5/v9-verified body)
__device__ void phase_gru(const Params& P, float* sm, int blk, int t) {
  float* sHr = sm;           // 544
  float* sHz = sm + 544;
  float* sHn = sm + 1088;
  float* sIr = sm + 1632;    // 64
  float* sIz = sm + 1696;
  float* sIn = sm + 1760;
  for (int pass = 0; pass < 2; ++pass) {
    const int h = blk + pass * 256;
    __syncthreads();
    if (t < 128)      stage_pad68(sHr, P.w_hh + h * 512, t);
    else if (t < 256) stage_pad68(sHz, P.w_hh + (h + 512) * 512, t - 128);
    else if (t < 384) stage_pad68(sHn, P.w_hh + (h + 1024) * 512, t - 256);
    else if (t < 400) ((float4*)sIr)[t - 384] = ((const float4*)(P.w_ih + h * 64))[t - 384];
    else if (t < 416) ((float4*)sIz)[t - 400] = ((const float4*)(P.w_ih + (h + 512) * 64))[t - 400];
    else if (t < 432) ((float4*)sIn)[t - 416] = ((const float4*)(P.w_ih + (h + 1024) * 64))[t - 416];
    __syncthreads();
    const int bi = t >> 3, kg = t & 7;
    float pr = 0.f, pz = 0.f, pin = 0.f, phn = 0.f;
    {
      const float* mrow = P.message + bi * 64 + kg * 8;
      const float* ir = &sIr[kg * 8];
      const float* iz = &sIz[kg * 8];
      const float* in_ = &sIn[kg * 8];
      #pragma unroll
      for (int i = 0; i < 2; ++i) {
        float4 x = *(const float4*)&mrow[i * 4];
        float4 wr = *(const float4*)&ir[i * 4];
        float4 wz = *(const float4*)&iz[i * 4];
        float4 wn = *(const float4*)&in_[i * 4];
        pr = fmaf(x.x, wr.x, pr); pr = fmaf(x.y, wr.y, pr); pr = fmaf(x.z, wr.z, pr); pr = fmaf(x.w, wr.w, pr);
        pz = fmaf(x.x, wz.x, pz); pz = fmaf(x.y, wz.y, pz); pz = fmaf(x.z, wz.z, pz); pz = fmaf(x.w, wz.w, pz);
        pin = fmaf(x.x, wn.x, pin); pin = fmaf(x.y, wn.y, pin); pin = fmaf(x.z, wn.z, pin); pin = fmaf(x.w, wn.w, pin);
      }
    }
    {
      const float* srow = P.state + bi * 512 + kg * 64;
      const float* hr = &sHr[kg * 68];
      const float* hz = &sHz[kg * 68];
      const float* hn = &sHn[kg * 68];
      #pragma unroll
      for (int i = 0; i < 16; ++i) {
        float4 x = *(const float4*)&srow[i * 4];
        float4 wr = *(const float4*)&hr[i * 4];
        float4 wz = *(const float4*)&hz[i * 4];
        float4 wn = *(const float4*)&hn[i * 4];
        pr = fmaf(x.x, wr.x, pr); pr = fmaf(x.y, wr.y, pr); pr = fmaf(x.z, wr.z, pr); pr = fmaf(x.w, wr.w, pr);
        pz = fmaf(x.x, wz.x, pz); pz = fmaf(x.y, wz.y, pz); pz = fmaf(x.z, wz.z, pz); pz = fmaf(x.w, wz.w, pz);
        phn = fmaf(x.x, wn.x, phn); phn = fmaf(x.y, wn.y, phn); phn = fmaf(x.z, wn.z, phn); phn = fmaf(x.w, wn.w, phn);
      }
    }
    pr += __shfl_xor(pr, 1, 8); pr += __shfl_xor(pr, 2, 8); pr += __shfl_xor(pr, 4, 8);
    pz += __shfl_xor(pz, 1, 8); pz += __shfl_xor(pz, 2, 8); pz += __shfl_xor(pz, 4, 8);
    pin += __shfl_xor(pin, 1, 8); pin += __shfl_xor(pin, 2, 8); pin += __shfl_xor(pin, 4, 8);
    phn += __shfl_xor(phn, 1, 8); phn += __shfl_xor(phn, 2, 8); phn += __shfl_xor(phn, 4, 8);
    if ((t & 7) == 0) {
      float r = sigm(pr + P.b_ih[h] + P.b_hh[h]);
      float z = sigm(pz + P.b_ih[h + 512] + P.b_hh[h + 512]);
      float n = tanhf(pin + P.b_ih[h + 1024] + r * (phn + P.b_hh[h + 1024]));
      float hp = P.state[bi * 512 + h];
      float v = (1.0f - z) * n + z * hp;
      P.ns[bi * 512 + h] = v;
      P.nsT[h * 64 + bi] = v;
    }
  }
}

// ---------------- Phase A2: ws1 rows j = 2blk, 2blk+1 (waves 0-1; reg-only).
__device__ void phase_ws1(const Params& P, int blk, int t) {
  const int g8 = t >> 6;
  if (g8 < 2) {
    const int j = blk * 2 + g8;
    const int lane = t & 63;
    const float* row = P.w_y1 + j * 1024 + lane * 8;
    float4 a = *(const float4*)&row[0];
    float4 b = *(const float4*)&row[4];
    float acc = a.x + a.y + a.z + a.w + b.x + b.y + b.z + b.w;
    #pragma unroll
    for (int m = 1; m < 64; m <<= 1) acc += __shfl_xor(acc, m, 64);
    if (lane == 0) P.ws1[j] = acc;
  }
}

// ---------------- Phase A3: g tile q=blk. 64x64, BK=32, 2x4 acc, swizzled LDS.
__device__ void phase_g(const Params& P, float* sm, int blk, int t, float* G) {
  float* As = sm;          // [32][68] swizzled
  float* Bs = sm + 2176;   // [32][68] swizzled
  const int rr0 = (blk >> 3) * 64;
  const int j0 = (blk & 7) * 64;
  const int lrow = t >> 3;          // 0..63
  const int lk4 = (t & 7) * 4;      // 0..28
  const int swz = (t & 7) << 2;     // (k>>2)<<2 for this thread's k-quad
  const int sc = lrow ^ swz;        // swizzled store col (stays < 64)
  const int tm2 = (t >> 4) * 2;     // 0..62
  const int tn4 = (t & 15) * 4;     // 0..60
  const float* aptr = P.desc + (rr0 + lrow) * 512 + lk4;
  const float* bptr = P.w_y1 + (j0 + lrow) * 1024 + 512 + lk4;
  float4 av = *(const float4*)aptr;
  float4 bv = *(const float4*)bptr;
  float acc[2][4] = {};
  for (int k0 = 0; k0 < 512; k0 += 32) {
    __syncthreads();
    As[(lk4 + 0) * 68 + sc] = av.x; As[(lk4 + 1) * 68 + sc] = av.y;
    As[(lk4 + 2) * 68 + sc] = av.z; As[(lk4 + 3) * 68 + sc] = av.w;
    Bs[(lk4 + 0) * 68 + sc] = bv.x; Bs[(lk4 + 1) * 68 + sc] = bv.y;
    Bs[(lk4 + 2) * 68 + sc] = bv.z; Bs[(lk4 + 3) * 68 + sc] = bv.w;
    __syncthreads();
    if (k0 + 32 < 512) {
      av = *(const float4*)(aptr + k0 + 32);
      bv = *(const float4*)(bptr + k0 + 32);
    }
    #pragma unroll
    for (int k = 0; k < 32; ++k) {
      const int swzk = (k >> 2) << 2;
      float2 a = *(const float2*)&As[k * 68 + (tm2 ^ swzk)];
      float4 b = *(const float4*)&Bs[k * 68 + (tn4 ^ swzk)];
      acc[0][0] = fmaf(a.x, b.x, acc[0][0]); acc[0][1] = fmaf(a.x, b.y, acc[0][1]);
      acc[0][2] = fmaf(a.x, b.z, acc[0][2]); acc[0][3] = fmaf(a.x, b.w, acc[0][3]);
      acc[1][0] = fmaf(a.y, b.x, acc[1][0]); acc[1][1] = fmaf(a.y, b.y, acc[1][1]);
      acc[1][2] = fmaf(a.y, b.z, acc[1][2]); acc[1][3] = fmaf(a.y, b.w, acc[1][3]);
    }
  }
  float4 by = *(const float4*)&P.b_y1[j0 + tn4];
  float4 r0 = make_float4(acc[0][0] + by.x, acc[0][1] + by.y, acc[0][2] + by.z, acc[0][3] + by.w);
  float4 r1 = make_float4(acc[1][0] + by.x, acc[1][1] + by.y, acc[1][2] + by.z, acc[1][3] + by.w);
  *(float4*)&G[(rr0 + tm2) * 512 + j0 + tn4] = r0;
  *(float4*)&G[(rr0 + tm2 + 1) * 512 + j0 + tn4] = r1;
}

// ---------------- Phase B: y. Two q-jobs per block (q = 2blk+half). (v9 body)
__device__ void phase_y(const Params& P, float* sm, int blk, int t, const float* G) {
  float* sW1 = sm;            // 512 (shared by both halves)
  float* sW2 = sm + 512;      // 512
  const int half = t >> 8, tl = t & 255;
  float* base = sm + 1024 + half * 3136;
  float* sG = base;           // 2048
  float* sV = base + 2048;    // 64
  float* sp = base + 2112;    // 1024
  const int q = blk * 2 + half;
  ((float4*)sG)[tl] = ((const float4*)(G + q * 2048))[tl];
  ((float4*)sG)[tl + 256] = ((const float4*)(G + q * 2048))[tl + 256];
  if (half == 0) {
    if (tl < 128) ((float4*)sW1)[tl] = ((const float4*)P.ws1)[tl];
    else          ((float4*)sW2)[tl - 128] = ((const float4*)P.w_y2)[tl - 128];
  }
  if (tl < 64) sV[tl] = P.nsT[q * 64 + tl];
  __syncthreads();
  const int bi = tl & 63, jq = tl >> 6;
  const float v = sV[bi];
  const float* g0 = sG + jq * 128;
  const float* g1 = sG + 512 + jq * 128;
  const float* g2 = sG + 1024 + jq * 128;
  const float* g3 = sG + 1536 + jq * 128;
  const float* w1 = sW1 + jq * 128;
  const float* w2 = sW2 + jq * 128;
  float a0 = 0.f, a1 = 0.f, a2 = 0.f, a3 = 0.f;
  #pragma unroll 4
  for (int j = 0; j < 128; j += 4) {
    float4 x1 = *(const float4*)&w1[j];
    float4 x2 = *(const float4*)&w2[j];
    float4 G0 = *(const float4*)&g0[j];
    float4 G1 = *(const float4*)&g1[j];
    float4 G2 = *(const float4*)&g2[j];
    float4 G3 = *(const float4*)&g3[j];
    float tj;
    tj = v * x1.x;
    a0 = fmaf(x2.x, fmaxf(tj + G0.x, 0.f), a0);
    a1 = fmaf(x2.x, fmaxf(tj + G1.x, 0.f), a1);
    a2 = fmaf(x2.x, fmaxf(tj + G2.x, 0.f), a2);
    a3 = fmaf(x2.x, fmaxf(tj + G3.x, 0.f), a3);
    tj = v * x1.y;
    a0 = fmaf(x2.y, fmaxf(tj + G0.y, 0.f), a0);
    a1 = fmaf(x2.y, fmaxf(tj + G1.y, 0.f), a1);
    a2 = fmaf(x2.y, fmaxf(tj + G2.y, 0.f), a2);
    a3 = fmaf(x2.y, fmaxf(tj + G3.y, 0.f), a3);
    tj = v * x1.z;
    a0 = fmaf(x2.z, fmaxf(tj + G0.z, 0.f), a0);
    a1 = fmaf(x2.z, fmaxf(tj + G1.z, 0.f), a1);
    a2 = fmaf(x2.z, fmaxf(tj + G2.z, 0.f), a2);
    a3 = fmaf(x2.z, fmaxf(tj + G3.z, 0.f), a3);
    tj = v * x1.w;
    a0 = fmaf(x2.w, fmaxf(tj + G0.w, 0.f), a0);
    a1 = fmaf(x2.w, fmaxf(tj + G1.w, 0.f), a1);
    a2 = fmaf(x2.w, fmaxf(tj + G2.w, 0.f), a2);
    a3 = fmaf(x2.w, fmaxf(tj + G3.w, 0.f), a3);
  }
  sp[(0 * 4 + jq) * 64 + bi] = a0;
  sp[(1 * 4 + jq) * 64 + bi] = a1;
  sp[(2 * 4 + jq) * 64 + bi] = a2;
  sp[(3 * 4 + jq) * 64 + bi] = a3;
  __syncthreads();
  const int rl = tl >> 6, b2 = tl & 63;
  float y = sp[(rl * 4 + 0) * 64 + b2] + sp[(rl * 4 + 1) * 64 + b2]
          + sp[(rl * 4 + 2) * 64 + b2] + sp[(rl * 4 + 3) * 64 + b2] + P.b_y2[0];
  P.out_y[b2 * 2048 + 4 * q + rl] = y;
}

// ---------------- Phase C: dp = exp(y) @ desc chunk (+ row sums on d-tile 0).
__device__ void phase_dipart(const Params& P, float* sm, int blk, int t) {
  float* sE = sm;          // 64*66
  float* sD = sm + 4224;   // 64*68
  const int jobd = blk >> 5, jobn = blk & 31;
  const int d0 = jobd * 64;
  const int n0 = jobn * 64;
  {
    const int bi = t >> 3;
    const int kq8 = (t & 7) * 8;
    float4 av = *(const float4*)&P.out_y[bi * 2048 + n0 + kq8];
    float4 bv = *(const float4*)&P.out_y[bi * 2048 + n0 + kq8 + 4];
    float e0 = expf(av.x), e1 = expf(av.y), e2 = expf(av.z), e3 = expf(av.w);
    float e4 = expf(bv.x), e5 = expf(bv.y), e6 = expf(bv.z), e7 = expf(bv.w);
    sE[(kq8 + 0) * 66 + bi] = e0; sE[(kq8 + 1) * 66 + bi] = e1;
    sE[(kq8 + 2) * 66 + bi] = e2; sE[(kq8 + 3) * 66 + bi] = e3;
    sE[(kq8 + 4) * 66 + bi] = e4; sE[(kq8 + 5) * 66 + bi] = e5;
    sE[(kq8 + 6) * 66 + bi] = e6; sE[(kq8 + 7) * 66 + bi] = e7;
    float psum = e0 + e1 + e2 + e3 + e4 + e5 + e6 + e7;
    psum += __shfl_xor(psum, 1, 8); psum += __shfl_xor(psum, 2, 8); psum += __shfl_xor(psum, 4, 8);
    if (jobd == 0 && (t & 7) == 0) P.sump[jobn * 64 + bi] = psum;
    const int nn = t >> 3, dq8 = (t & 7) * 8;
    *(float4*)&sD[nn * 68 + dq8] = *(const float4*)&P.desc[(n0 + nn) * 512 + d0 + dq8];
    *(float4*)&sD[nn * 68 + dq8 + 4] = *(const float4*)&P.desc[(n0 + nn) * 512 + d0 + dq8 + 4];
  }
  __syncthreads();
  const int bi0 = (t >> 4) * 2;
  const int dd0 = (t & 15) * 4;
  float acc[2][4] = {};
  #pragma unroll 8
  for (int nn = 0; nn < 64; ++nn) {
    float2 a = *(const float2*)&sE[nn * 66 + bi0];
    float4 b = *(const float4*)&sD[nn * 68 + dd0];
    acc[0][0] = fmaf(a.x, b.x, acc[0][0]); acc[0][1] = fmaf(a.x, b.y, acc[0][1]);
    acc[0][2] = fmaf(a.x, b.z, acc[0][2]); acc[0][3] = fmaf(a.x, b.w, acc[0][3]);
    acc[1][0] = fmaf(a.y, b.x, acc[1][0]); acc[1][1] = fmaf(a.y, b.y, acc[1][1]);
    acc[1][2] = fmaf(a.y, b.z, acc[1][2]); acc[1][3] = fmaf(a.y, b.w, acc[1][3]);
  }
  float* base = P.dp + jobn * 32768;
  *(float4*)&base[(bi0 + 0) * 512 + d0 + dd0] = make_float4(acc[0][0], acc[0][1], acc[0][2], acc[0][3]);
  *(float4*)&base[(bi0 + 1) * 512 + d0 + dd0] = make_float4(acc[1][0], acc[1][1], acc[1][2], acc[1][3]);
}

// ---------------- Phase D: di = (sum_c dp[c]) / sum. Blocks 0..63 (bi=blk).
__device__ void phase_direduce(const Params& P, float* sm, int blk, int t) {
  if (blk >= 64) return;
  const int bi = blk;
  float* sInv = sm;
  if (t < 32) {
    float s = P.sump[t * 64 + bi];
    s += __shfl_xor(s, 1, 32); s += __shfl_xor(s, 2, 32);
    s += __shfl_xor(s, 4, 32); s += __shfl_xor(s, 8, 32);
    s += __shfl_xor(s, 16, 32);
    if (t == 0) sInv[0] = 1.0f / s;
  }
  __syncthreads();
  const float inv = sInv[0];
  float acc = 0.0f;
  #pragma unroll 8
  for (int c = 0; c < 32; ++c) acc += P.dp[c * 32768 + bi * 512 + t];
  P.di[bi * 512 + t] = acc * inv;
}

// ---------------- Phase E: message_state. hj = blk, blk+256. (v9 body)
__device__ void phase_ms(const Params& P, float* sm, int blk, int t) {
  float* sWs = sm;        // 544
  float* sWd = sm + 544;  // 544
  for (int pass = 0; pass < 2; ++pass) {
    const int hj = blk + pass * 256;
    __syncthreads();
    if (t < 128)      stage_pad68(sWs, P.w_state + hj * 512, t);
    else if (t < 256) stage_pad68(sWd, P.w_desc + hj * 512, t - 128);
    __syncthreads();
    const int bi = t >> 3, kg = t & 7;
    const float* nr = P.ns + bi * 512 + kg * 64;
    const float* dr = P.di + bi * 512 + kg * 64;
    const float* wsp = &sWs[kg * 68];
    const float* wdp = &sWd[kg * 68];
    float acc = 0.f;
    #pragma unroll
    for (int i = 0; i < 16; ++i) {
      float4 a = *(const float4*)&nr[i * 4];
      float4 w = *(const float4*)&wsp[i * 4];
      float4 b = *(const float4*)&dr[i * 4];
      float4 u = *(const float4*)&wdp[i * 4];
      acc = fmaf(a.x, w.x, acc); acc = fmaf(a.y, w.y, acc);
      acc = fmaf(a.z, w.z, acc); acc = fmaf(a.w, w.w, acc);
      acc = fmaf(b.x, u.x, acc); acc = fmaf(b.y, u.y, acc);
      acc = fmaf(b.z, u.z, acc); acc = fmaf(b.w, u.w, acc);
    }
    acc += __shfl_xor(acc, 1, 8); acc += __shfl_xor(acc, 2, 8); acc += __shfl_xor(acc, 4, 8);
    if ((t & 7) == 0) P.ms[bi * 512 + hj] = tanhf(acc + P.b_state[hj]);
  }
}

// ---------------- Phase F: msg (blocks 0..63, m=blk) + stop (block 64).
__device__ void phase_msgstop(const Params& P, float* sm, int blk, int t) {
  if (blk == 64) {  // stop head
    const int bi = t >> 3, kg = t & 7;
    const float* row = P.ns + bi * 512 + kg * 64;
    const float* wrow = P.w_stop + kg * 64;
    float acc = 0.f;
    #pragma unroll
    for (int i = 0; i < 16; ++i) {
      float4 r = *(const float4*)&row[i * 4];
      float4 w = *(const float4*)&wrow[i * 4];
      acc = fmaf(r.x, w.x, acc); acc = fmaf(r.y, w.y, acc);
      acc = fmaf(r.z, w.z, acc); acc = fmaf(r.w, w.w, acc);
    }
    acc += __shfl_xor(acc, 1, 8); acc += __shfl_xor(acc, 2, 8); acc += __shfl_xor(acc, 4, 8);
    if ((t & 7) == 0) {
      float sd = sigm(acc + P.b_stop[0]);
      P.out_stopdist[bi] = sd;
      P.out_stopbit[bi] = rintf(sd);
    }
    return;
  }
  if (blk >= 64) return;
  float* sW = sm;  // 544
  if (t < 128) stage_pad68(sW, P.w_msg + blk * 512, t);
  __syncthreads();
  const int bi = t >> 3, kg = t & 7;
  const float* row = P.ms + bi * 512 + kg * 64;
  const float* wp = &sW[kg * 68];
  float acc = 0.f;
  #pragma unroll
  for (int i = 0; i < 16; ++i) {
    float4 a = *(const float4*)&row[i * 4];
    float4 w = *(const float4*)&wp[i * 4];
    acc = fmaf(a.x, w.x, acc); acc = fmaf(a.y, w.y, acc);
    acc = fmaf(a.z, w.z, acc); acc = fmaf(a.w, w.w, acc);
  }
  acc += __shfl_xor(acc, 1, 8); acc += __shfl_xor(acc, 2, 8); acc += __shfl_xor(acc, 4, 8);
  if ((t & 7) == 0) {
    float md = sigm(acc + P.b_msg[blk]);
    P.out_msgdist[bi * 64 + blk] = md;
    P.out_msg[bi * 64 + blk] = rintf(md);
  }
}

// ---------------- fused persistent kernel: 256 blocks x 512 threads.
__global__ __launch_bounds__(512, 1) void fused_kernel(Params P) {
  __shared__ float sm[8576];  // 34.3 KB, max over phases (dipart)
  const int blk = blockIdx.x, t = threadIdx.x;
  // Phase A: gru + ws1 + g — g is independent of gru, no grid barrier needed.
  phase_gru(P, sm, blk, t);
  phase_ws1(P, blk, t);
  phase_g(P, sm, blk, t, P.dp);   // G shares the dp buffer (dp used later)
  grid_barrier(P.bar);
  phase_y(P, sm, blk, t, P.dp);   // reads G
  grid_barrier(P.bar);
  phase_dipart(P, sm, blk, t);    // overwrites dp (G dead after phase_y)
  grid_barrier(P.bar);
  phase_direduce(P, sm, blk, t);
  grid_barrier(P.bar);
  phase_ms(P, sm, blk, t);
  grid_barrier(P.bar);
  phase_msgstop(P, sm, blk, t);
}

extern "C" void kernel_launch(void* const* d_in, const int* in_sizes, int n_in,
                              void* d_out, int out_size, void* d_ws, size_t ws_size,
                              hipStream_t stream) {
  (void)in_sizes; (void)n_in; (void)out_size; (void)ws_size;
  float* out = (float*)d_out;
  char* ws = (char*)d_ws;

  Params p;
  p.message = (const float*)d_in[0];
  p.state   = (const float*)d_in[1];
  // d_in[2] "image" unused by the reference.
  p.desc    = (const float*)d_in[3];
  p.w_ih    = (const float*)d_in[4];
  p.w_hh    = (const float*)d_in[5];
  p.b_ih    = (const float*)d_in[6];
  p.b_hh    = (const float*)d_in[7];
  p.w_stop  = (const float*)d_in[8];
  p.b_stop  = (const float*)d_in[9];
  p.w_y1    = (const float*)d_in[10];
  p.b_y1    = (const float*)d_in[11];
  p.w_y2    = (const float*)d_in[12];
  p.b_y2    = (const float*)d_in[13];
  p.w_state = (const float*)d_in[14];
  p.b_state = (const float*)d_in[15];
  p.w_desc  = (const float*)d_in[16];
  p.w_msg   = (const float*)d_in[17];
  p.b_msg   = (const float*)d_in[18];

  p.out_stopbit  = out;          // [64]
  p.out_stopdist = out + 64;     // [64]
  p.out_msg      = out + 128;    // [64*64]
  p.out_msgdist  = out + 4224;   // [64*64]
  p.out_y        = out + 8320;   // [64*2048]

  p.ns   = (float*)(ws);             // 64*512
  p.nsT  = (float*)(ws + 131072);    // 512*64
  p.ws1  = (float*)(ws + 262144);    // 512
  p.dp   = (float*)(ws + 264192);    // 2048*512 (G, then di partials)
  p.sump = (float*)(ws + 4458496);   // 32*64
  p.di   = (float*)(ws + 4466688);   // 64*512
  p.ms   = (float*)(ws + 4597760);   // 64*512
  p.bar  = (int*)(ws + 4728832);     // 2 ints

  (void)hipMemsetAsync(p.bar, 0, 2 * sizeof(int), stream);
  fused_kernel<<<NBLK, 512, 0, stream>>>(p);
}